// Round 14
// baseline (347.737 us; speedup 1.0000x reference)
//
#include <hip/hip_runtime.h>

typedef short bf16x8 __attribute__((ext_vector_type(8)));
typedef float f32x4  __attribute__((ext_vector_type(4)));
typedef unsigned short ushort_t;

__device__ __forceinline__ float silu(float x) {
    float t = __expf(-x);
    return x * __builtin_amdgcn_rcpf(1.f + t);
}

__device__ __forceinline__ ushort_t f2bs(float x) {
    union { float f; unsigned int u; } v; v.f = x;
    unsigned int r = v.u + 0x7FFF + ((v.u >> 16) & 1);
    return (ushort_t)(r >> 16);
}
__device__ __forceinline__ ushort_t f2bs_t(float x) {
    union { float f; unsigned int u; } v; v.f = x;
    return (ushort_t)(v.u >> 16);
}
__device__ __forceinline__ float bs2f(ushort_t x) {
    union { unsigned int u; float f; } v; v.u = ((unsigned int)x) << 16; return v.f;
}

// lgkm-only barrier: orders LDS ops across the workgroup WITHOUT draining
// vmcnt — global loads stay in flight across GEMM phases (T4 principle).
#define BAR_LGKM() do { \
    asm volatile("s_waitcnt lgkmcnt(0)" ::: "memory"); \
    __builtin_amdgcn_s_barrier(); \
} while (0)

constexpr int N_   = 16000;
constexpr int E_   = 256000;
constexpr int Fd   = 64;

constexpr float SQ3f    = 1.7320508075688772f;
constexpr float INV_SQ3 = 0.5773502691896258f;
constexpr float INV_SQ2 = 0.7071067811865476f;
constexpr float INV_AVG = 0.0625f;

constexpr int OFF_OS = 0;
constexpr int OFF_OV = N_;
constexpr int OFF_PS = OFF_OV + 3 * N_;
constexpr int OFF_PV = OFF_PS + N_ * Fd;

constexpr int W1P_SZ = 6 * 8 * 512;
constexpr int W2P_SZ = 4 * 8 * 512;
constexpr int W3P_SZ = 4 * 12 * 512;

// agg layout per node: [cs | kx | ky | kz | c0 | c1 | c2] x 64 features, f32
constexpr int AGG_W = 448;

// Single-union LDS: A/mix @0 stride 200 (12800 u = 25.6 KB); H1/H2 share @0
// stride 136 (GEMM2 carries outputs in registers across a barrier).
// launch_bounds (256,4): R7-R10 bisect showed the 2nd arg IS the effective
// residency; (256,4) is the verified clean operating point.
// R6/R11/R12 lesson: phase-4 h_v consumption must stay SoA — three layout
// variants (AoS float3, f32-h_s float4, bit-identical float4) all failed
// absmax on p_s; mechanism undiagnosed, path closed.
constexpr int U_SZ = 12800;

// pack grid: 256 packing blocks + 448 zeroing blocks (agg + cnt)
constexpr int PACK_B  = 256;
constexpr int ZERO_B  = 448;
constexpr int AGG_F4  = (N_ * AGG_W) / 4;   // 1,792,000 float4
constexpr int CNT_I4  = N_ / 4;             // 4,000 int4

// ---------------------------------------------------------------------------
// pack weights fp32 -> bf16 MFMA B-fragment order; blocks >= PACK_B zero
// agg + cnt (replaces two hipMemsetAsync dispatches). Runs FIRST.
// ---------------------------------------------------------------------------
__global__ __launch_bounds__(256) void pack_kernel(
    const float* __restrict__ W1, const float* __restrict__ W2,
    const float* __restrict__ W3,
    ushort_t* __restrict__ W1p, ushort_t* __restrict__ W2p,
    ushort_t* __restrict__ W3p,
    float* __restrict__ agg, int* __restrict__ cnt)
{
    if (blockIdx.x >= PACK_B) {
        const int zb = blockIdx.x - PACK_B;
        const float4 zf = make_float4(0.f, 0.f, 0.f, 0.f);
        for (size_t i = (size_t)zb * 256 + threadIdx.x; i < (size_t)AGG_F4;
             i += (size_t)ZERO_B * 256)
            ((float4*)agg)[i] = zf;
        for (int i = zb * 256 + threadIdx.x; i < CNT_I4; i += ZERO_B * 256)
            ((int4*)cnt)[i] = make_int4(0, 0, 0, 0);
        return;
    }
    int idx = blockIdx.x * 256 + threadIdx.x;
    if (idx < W1P_SZ) {
        int j = idx & 7, lane = (idx >> 3) & 63, tile = idx >> 9;
        int c = tile >> 3, t = tile & 7;
        int k = c * 32 + (lane >> 4) * 8 + j;
        int n = t * 16 + (lane & 15);
        W1p[idx] = f2bs(k < 161 ? W1[k * 128 + n] : 0.f);
    } else if (idx < W1P_SZ + W2P_SZ) {
        int q = idx - W1P_SZ;
        int j = q & 7, lane = (q >> 3) & 63, tile = q >> 9;
        int c = tile >> 3, t = tile & 7;
        int k = c * 32 + (lane >> 4) * 8 + j;
        int n = t * 16 + (lane & 15);
        W2p[q] = f2bs(W2[k * 128 + n]);
    } else {
        int q = idx - W1P_SZ - W2P_SZ;
        int j = q & 7, lane = (q >> 3) & 63, tile = q >> 9;
        int c = tile / 12, t = tile % 12;
        int k = c * 32 + (lane >> 4) * 8 + j;
        int n = t * 16 + (lane & 15);
        W3p[q] = f2bs(W3[k * 192 + n]);
    }
}

// ---------------------------------------------------------------------------
// Kernel 1: up-projection, 4 nodes/block. h_s bf16; h_v fp32 SoA (verified
// layout: h_v[n*192 + c*64 + g]). Fused receiver-count.
// ---------------------------------------------------------------------------
__global__ __launch_bounds__(64, 4) void up_kernel(
    const float* __restrict__ node_s, const float* __restrict__ node_v,
    const float* __restrict__ W_up_s, const float* __restrict__ b_up_s,
    const float* __restrict__ W_up_v,
    const int* __restrict__ receivers, int* __restrict__ cnt,
    ushort_t* __restrict__ hs_bf, float* __restrict__ h_v)
{
    __shared__ float ns[4][64];
    __shared__ float nv[4][64][3];
    const int n0 = blockIdx.x * 4;
    const int g  = threadIdx.x;

    {
        int e = blockIdx.x * 64 + g;
        atomicAdd(&cnt[receivers[e]], 1);
    }

    #pragma unroll
    for (int j = 0; j < 4; j++) ns[j][g] = node_s[(n0 + j) * 64 + g];
    for (int idx = g; idx < 4 * 192; idx += 64) {
        int j = idx / 192, r = idx - j * 192;
        nv[j][r / 3][r % 3] = node_v[(size_t)n0 * 192 + idx];
    }
    __syncthreads();

    float as[4], a0[4], a1[4], a2[4];
    float bb = b_up_s[g];
    #pragma unroll
    for (int j = 0; j < 4; j++) { as[j] = bb; a0[j] = a1[j] = a2[j] = 0.f; }
    #pragma unroll 4
    for (int f = 0; f < 64; f++) {
        float wss = W_up_s[f * 64 + g];
        float wv  = W_up_v[f * 64 + g];
        #pragma unroll
        for (int j = 0; j < 4; j++) {
            as[j] += ns[j][f] * wss;
            a0[j] += nv[j][f][0] * wv;
            a1[j] += nv[j][f][1] * wv;
            a2[j] += nv[j][f][2] * wv;
        }
    }
    #pragma unroll
    for (int j = 0; j < 4; j++) {
        hs_bf[(n0 + j) * 64 + g] = f2bs(as[j]);
        h_v[(n0 + j) * 192 + 0 * 64 + g] = a0[j];
        h_v[(n0 + j) * 192 + 1 * 64 + g] = a1[j];
        h_v[(n0 + j) * 192 + 2 * 64 + g] = a2[j];
    }
}

// ---------------------------------------------------------------------------
// CSR scan
// ---------------------------------------------------------------------------
__global__ __launch_bounds__(1024) void scan_kernel(
    const int* __restrict__ cnt, int* __restrict__ base, int* __restrict__ cursor)
{
    __shared__ int part[1024];
    const int t = threadIdx.x;
    int v[16];
    int s = 0;
    if (t < 1000) {
        const int4* c4 = (const int4*)(cnt + t * 16);
        #pragma unroll
        for (int q = 0; q < 4; q++) {
            int4 w = c4[q];
            v[q * 4 + 0] = w.x; v[q * 4 + 1] = w.y;
            v[q * 4 + 2] = w.z; v[q * 4 + 3] = w.w;
            s += w.x + w.y + w.z + w.w;
        }
    }
    part[t] = s;
    __syncthreads();
    for (int off = 1; off < 1024; off <<= 1) {
        int u = (t >= off) ? part[t - off] : 0;
        __syncthreads();
        part[t] += u;
        __syncthreads();
    }
    if (t < 1000) {
        int run = part[t] - s;
        int b[16];
        #pragma unroll
        for (int i = 0; i < 16; i++) { b[i] = run; run += v[i]; }
        int4* bb = (int4*)(base + t * 16);
        int4* cc = (int4*)(cursor + t * 16);
        #pragma unroll
        for (int q = 0; q < 4; q++) {
            int4 w = { b[q * 4], b[q * 4 + 1], b[q * 4 + 2], b[q * 4 + 3] };
            bb[q] = w;
            cc[q] = w;
        }
    }
}

// ---------------------------------------------------------------------------
// inverse permutation: eid[p] = original edge id of sorted position p
// ---------------------------------------------------------------------------
__global__ __launch_bounds__(256) void perm_kernel(
    const int* __restrict__ receivers, int* __restrict__ cursor,
    int* __restrict__ eid)
{
    int e = blockIdx.x * 256 + threadIdx.x;
    int r = receivers[e];
    int p = atomicAdd(&cursor[r], 1);
    eid[p] = e;
}

// ---------------------------------------------------------------------------
// Kernel 2: cooperative MFMA edge MLP over CSR-SORTED edges + in-register
// segmented reduction. Single 25.6 KB union LDS; (256,4) launch_bounds.
// T5: s_setprio(1) wraps each MFMA cluster — co-resident blocks sit at
// different phases, so MFMA-phase waves preempt staging/aggregating waves
// from other blocks (scheduling-only; zero numerics/layout change).
// ---------------------------------------------------------------------------
__global__ __launch_bounds__(256, 4) void edge_mlp_kernel(
    const float* __restrict__ lengths, const float* __restrict__ sef,
    const int* __restrict__ senders, const int* __restrict__ receivers,
    const float* __restrict__ vectors, const int* __restrict__ eid,
    const float* __restrict__ b1f, const float* __restrict__ b2f,
    const float* __restrict__ b3f,
    const ushort_t* __restrict__ hs_bf, const float* __restrict__ h_v,
    const ushort_t* __restrict__ W1p, const ushort_t* __restrict__ W2p,
    const ushort_t* __restrict__ W3p,
    float* __restrict__ agg)
{
    __shared__ ushort_t U[U_SZ];    // A/mix (stride 200) | H1/H2 @0 (stride 136)
    __shared__ int snd_s[64];
    __shared__ int rcv_s[64];
    __shared__ float ev_s[64][3];

    const int tid  = threadIdx.x;
    const int wave = tid >> 6, lane = tid & 63;
    const int quad = lane >> 4, l4 = lane & 15;
    const int e0   = blockIdx.x * 64;   // sorted-position base

    if (tid < 64) {
        int e = eid[e0 + tid];
        snd_s[tid] = senders[e];
        rcv_s[tid] = receivers[e];
        ev_s[tid][0] = SQ3f * vectors[e * 3 + 0];
        ev_s[tid][1] = SQ3f * vectors[e * 3 + 1];
        ev_s[tid][2] = SQ3f * vectors[e * 3 + 2];
    }

    // ---- stage mlp_in rows (sorted order): 64 edges x 192 bf16 (pad 200) ----
    {
        const int e  = tid & 63;
        const int ge = eid[e0 + e];
        const int snd = senders[ge];
        const int rcv = receivers[ge];
        for (int c = tid >> 6; c < 24; c += 4) {
            bf16x8 v;
            if (c < 8) {
                v = *(const bf16x8*)(hs_bf + snd * 64 + c * 8);
            } else if (c < 16) {
                v = *(const bf16x8*)(hs_bf + rcv * 64 + (c - 8) * 8);
            } else if (c < 20) {
                const float4 s0 = *(const float4*)(sef + (size_t)ge * 32 + (c - 16) * 8);
                const float4 s1 = *(const float4*)(sef + (size_t)ge * 32 + (c - 16) * 8 + 4);
                v[0] = (short)f2bs(s0.x); v[1] = (short)f2bs(s0.y);
                v[2] = (short)f2bs(s0.z); v[3] = (short)f2bs(s0.w);
                v[4] = (short)f2bs(s1.x); v[5] = (short)f2bs(s1.y);
                v[6] = (short)f2bs(s1.z); v[7] = (short)f2bs(s1.w);
            } else if (c == 20) {
                v = (bf16x8){0,0,0,0,0,0,0,0};
                v[0] = (short)f2bs(lengths[ge]);
            } else {
                v = (bf16x8){0,0,0,0,0,0,0,0};
            }
            *(bf16x8*)(&U[e * 200 + c * 8]) = v;
        }
    }
    BAR_LGKM();   // (1) A + snd/rcv/ev ready

    const bf16x8* B1 = (const bf16x8*)W1p;
    const bf16x8* B2 = (const bf16x8*)W2p;
    const bf16x8* B3 = (const bf16x8*)W3p;

    // ---- GEMM1: wave owns N-tiles {2w, 2w+1}; M = 64 edges ----
    {
        f32x4 acc[2][4];
        #pragma unroll
        for (int ti = 0; ti < 2; ti++)
            #pragma unroll
            for (int m = 0; m < 4; m++) acc[ti][m] = (f32x4){0,0,0,0};
        __builtin_amdgcn_s_setprio(1);
        #pragma unroll
        for (int c = 0; c < 6; c++) {
            bf16x8 b0 = B1[(c * 8 + wave * 2 + 0) * 64 + lane];
            bf16x8 b1 = B1[(c * 8 + wave * 2 + 1) * 64 + lane];
            #pragma unroll
            for (int m = 0; m < 4; m++) {
                bf16x8 a = *(const bf16x8*)(&U[(m * 16 + l4) * 200 + c * 32 + quad * 8]);
                acc[0][m] = __builtin_amdgcn_mfma_f32_16x16x32_bf16(a, b0, acc[0][m], 0, 0, 0);
                acc[1][m] = __builtin_amdgcn_mfma_f32_16x16x32_bf16(a, b1, acc[1][m], 0, 0, 0);
            }
        }
        __builtin_amdgcn_s_setprio(0);
        BAR_LGKM();   // (2) all waves done reading A
        #pragma unroll
        for (int ti = 0; ti < 2; ti++) {
            int t = wave * 2 + ti;
            float bb = b1f[t * 16 + l4];
            #pragma unroll
            for (int m = 0; m < 4; m++)
                #pragma unroll
                for (int r = 0; r < 4; r++)
                    U[(m * 16 + quad * 4 + r) * 136 + t * 16 + l4] =
                        f2bs_t(silu(acc[ti][m][r] + bb));
        }
    }
    BAR_LGKM();   // (3) H1 ready

    // ---- GEMM2: read H1 @0; hold H2 in registers across barrier; write
    //      H2 @0 over H1 (single shared H region) ----
    {
        f32x4 acc[2][4];
        #pragma unroll
        for (int ti = 0; ti < 2; ti++)
            #pragma unroll
            for (int m = 0; m < 4; m++) acc[ti][m] = (f32x4){0,0,0,0};
        __builtin_amdgcn_s_setprio(1);
        #pragma unroll
        for (int c = 0; c < 4; c++) {
            bf16x8 b0 = B2[(c * 8 + wave * 2 + 0) * 64 + lane];
            bf16x8 b1 = B2[(c * 8 + wave * 2 + 1) * 64 + lane];
            #pragma unroll
            for (int m = 0; m < 4; m++) {
                bf16x8 a = *(const bf16x8*)(&U[(m * 16 + l4) * 136 + c * 32 + quad * 8]);
                acc[0][m] = __builtin_amdgcn_mfma_f32_16x16x32_bf16(a, b0, acc[0][m], 0, 0, 0);
                acc[1][m] = __builtin_amdgcn_mfma_f32_16x16x32_bf16(a, b1, acc[1][m], 0, 0, 0);
            }
        }
        __builtin_amdgcn_s_setprio(0);
        BAR_LGKM();   // (4) all waves done reading H1
        #pragma unroll
        for (int ti = 0; ti < 2; ti++) {
            int t = wave * 2 + ti;
            float bb = b2f[t * 16 + l4];
            #pragma unroll
            for (int m = 0; m < 4; m++)
                #pragma unroll
                for (int r = 0; r < 4; r++)
                    U[(m * 16 + quad * 4 + r) * 136 + t * 16 + l4] =
                        f2bs_t(silu(acc[ti][m][r] + bb));
        }
    }
    BAR_LGKM();   // (5) H2 ready

    // ---- GEMM3: read H2 @0; mix -> stride 200 @0 after barrier ----
    {
        f32x4 acc[3][4];
        #pragma unroll
        for (int ti = 0; ti < 3; ti++)
            #pragma unroll
            for (int m = 0; m < 4; m++) acc[ti][m] = (f32x4){0,0,0,0};
        __builtin_amdgcn_s_setprio(1);
        #pragma unroll
        for (int c = 0; c < 4; c++) {
            bf16x8 b0 = B3[(c * 12 + wave * 3 + 0) * 64 + lane];
            bf16x8 b1 = B3[(c * 12 + wave * 3 + 1) * 64 + lane];
            bf16x8 b2 = B3[(c * 12 + wave * 3 + 2) * 64 + lane];
            #pragma unroll
            for (int m = 0; m < 4; m++) {
                bf16x8 a = *(const bf16x8*)(&U[(m * 16 + l4) * 136 + c * 32 + quad * 8]);
                acc[0][m] = __builtin_amdgcn_mfma_f32_16x16x32_bf16(a, b0, acc[0][m], 0, 0, 0);
                acc[1][m] = __builtin_amdgcn_mfma_f32_16x16x32_bf16(a, b1, acc[1][m], 0, 0, 0);
                acc[2][m] = __builtin_amdgcn_mfma_f32_16x16x32_bf16(a, b2, acc[2][m], 0, 0, 0);
            }
        }
        __builtin_amdgcn_s_setprio(0);
        BAR_LGKM();   // (6) all waves done reading H2
        #pragma unroll
        for (int ti = 0; ti < 3; ti++) {
            int t = wave * 3 + ti;
            float bb = b3f[t * 16 + l4];
            #pragma unroll
            for (int m = 0; m < 4; m++)
                #pragma unroll
                for (int r = 0; r < 4; r++)
                    U[(m * 16 + quad * 4 + r) * 200 + t * 16 + l4] =
                        f2bs(acc[ti][m][r] + bb);
        }
    }
    BAR_LGKM();   // (7) mix ready

    // ---- Phase 4: segmented reduction over receiver runs (verified form,
    //      SoA scalar gathers, 8-deep batches). ----
    {
        const int g  = lane;
        const int p0 = wave * 16;
        float acc0 = 0.f, acc1 = 0.f, acc2 = 0.f, acc3 = 0.f;
        float acc4 = 0.f, acc5 = 0.f, acc6 = 0.f;
        int cur = rcv_s[p0];

        for (int jj = 0; jj < 16; jj += 8) {
            float M0[8], M1[8], M2[8], MS[8];
            #pragma unroll
            for (int j = 0; j < 8; j++) {
                const int se = snd_s[p0 + jj + j];
                M0[j] = h_v[(size_t)se * 192 + 0 * 64 + g];
                M1[j] = h_v[(size_t)se * 192 + 1 * 64 + g];
                M2[j] = h_v[(size_t)se * 192 + 2 * 64 + g];
                MS[j] = bs2f(hs_bf[se * 64 + g]);
            }
            #pragma unroll
            for (int j = 0; j < 8; j++) {
                const int el = p0 + jj + j;
                const int r  = rcv_s[el];
                if (r != cur) {
                    float* a = agg + (size_t)cur * AGG_W + g;
                    atomicAdd(a +   0, acc0); atomicAdd(a +  64, acc1);
                    atomicAdd(a + 128, acc2); atomicAdd(a + 192, acc3);
                    atomicAdd(a + 256, acc4); atomicAdd(a + 320, acc5);
                    atomicAdd(a + 384, acc6);
                    acc0 = acc1 = acc2 = acc3 = acc4 = acc5 = acc6 = 0.f;
                    cur = r;
                }
                const float ev0 = ev_s[el][0], ev1 = ev_s[el][1], ev2 = ev_s[el][2];
                const float mixs  = bs2f(U[el * 200 +   0 + g]);
                const float mixv1 = bs2f(U[el * 200 +  64 + g]);
                const float mixv2 = bs2f(U[el * 200 + 128 + g]);
                const float k = MS[j] * mixv1;
                acc0 += (M0[j] * ev0 + M1[j] * ev1 + M2[j] * ev2) * mixs;
                acc1 += k * ev0;
                acc2 += k * ev1;
                acc3 += k * ev2;
                acc4 += (M1[j] * ev2 - M2[j] * ev1) * mixv2;
                acc5 += (M2[j] * ev0 - M0[j] * ev2) * mixv2;
                acc6 += (M0[j] * ev1 - M1[j] * ev0) * mixv2;
            }
        }
        float* a = agg + (size_t)cur * AGG_W + g;
        atomicAdd(a +   0, acc0); atomicAdd(a +  64, acc1);
        atomicAdd(a + 128, acc2); atomicAdd(a + 192, acc3);
        atomicAdd(a + 256, acc4); atomicAdd(a + 320, acc5);
        atomicAdd(a + 384, acc6);
    }
}

// ---------------------------------------------------------------------------
// Kernel 3: node tail (verified form: 16 nodes/block, 4/wave, float4 LDS,
// zero barriers).
// ---------------------------------------------------------------------------
__global__ __launch_bounds__(256, 4) void node_fused_kernel(
    const float* __restrict__ agg,
    const int* __restrict__ specie,
    const float* __restrict__ W_dn_s, const float* __restrict__ b_dn_s,
    const float* __restrict__ W_dn_v,
    const float* __restrict__ w_sc_s, const float* __restrict__ w_sc_v,
    const float* __restrict__ W_pb_s, const float* __restrict__ b_pb_s,
    const float* __restrict__ W_pb_v,
    const float* __restrict__ W_r1_s, const float* __restrict__ b_r1_s,
    const float* __restrict__ W_r1_v,
    const float* __restrict__ W_r2_s, const float* __restrict__ b_r2,
    const float* __restrict__ W_r2_v,
    float* __restrict__ out)
{
    __shared__ float4 LD[16][64];   // A4 {as, av0..2 rows 0..63}, then SC4
    __shared__ float4 LE[16][64];   // B4 {0, av0..2 rows 64..127}, then P4

    const int tid = threadIdx.x;
    const int w   = tid >> 6;
    const int g   = tid & 63;
    const int nb  = blockIdx.x * 16 + w * 4;   // first node of this wave
    const int r0i = w * 4;                      // wave's LDS row base

    // ---- stage packed aggregates (coalesced 7 loads/node/lane) ----
    #pragma unroll
    for (int j = 0; j < 4; j++) {
        const float* ag = agg + (size_t)(nb + j) * AGG_W;
        float a0 = ag[g], a1 = ag[64 + g], a2 = ag[128 + g], a3 = ag[192 + g];
        float b1 = ag[256 + g], b2 = ag[320 + g], b3 = ag[384 + g];
        LD[r0i + j][g] = make_float4(a0 * (INV_SQ3 * INV_AVG),
                                     a1 * INV_AVG, a2 * INV_AVG, a3 * INV_AVG);
        LE[r0i + j][g] = make_float4(0.f,
                                     b1 * (INV_SQ2 * INV_AVG),
                                     b2 * (INV_SQ2 * INV_AVG),
                                     b3 * (INV_SQ2 * INV_AVG));
    }
    // wave-private LDS: no barrier needed anywhere in this kernel

    // ---- f_s = as @ W_dn_s ; f_v = av @ W_dn_v (128 rows folded 2x64) ----
    float fs[4], fv0[4], fv1[4], fv2[4];
    {
        float bds = b_dn_s[g];
        #pragma unroll
        for (int j = 0; j < 4; j++) { fs[j] = bds; fv0[j] = fv1[j] = fv2[j] = 0.f; }
    }
    #pragma unroll 4
    for (int f = 0; f < 64; f++) {
        float ws  = W_dn_s[f * 64 + g];
        float wva = W_dn_v[f * 64 + g];
        float wvb = W_dn_v[(64 + f) * 64 + g];
        #pragma unroll
        for (int j = 0; j < 4; j++) {
            float4 a = LD[r0i + j][f];
            float4 b = LE[r0i + j][f];
            fs[j]  += a.x * ws;
            fv0[j] += a.y * wva + b.y * wvb;
            fv1[j] += a.z * wva + b.z * wvb;
            fv2[j] += a.w * wva + b.w * wvb;
        }
    }

    // ---- elementwise specie mix; SC4 overwrites A4 (wave-private) ----
    #pragma unroll
    for (int j = 0; j < 4; j++) {
        int sp = specie[nb + j];
        float vv = (fv0[j] * fv0[j] + fv1[j] * fv1[j] + fv2[j] * fv2[j]) * INV_SQ3;
        float ws0 = w_sc_s[sp * 192 +   0 + g];
        float ws1 = w_sc_s[sp * 192 +  64 + g];
        float ws2 = w_sc_s[sp * 192 + 128 + g];
        float wv0 = w_sc_v[sp * 128 +   0 + g];
        float wv1 = w_sc_v[sp * 128 +  64 + g];
        float sc_s = ws0 * fs[j] + ws1 * fs[j] * fs[j] + ws2 * vv;
        float kv = wv0 + wv1 * fs[j];
        LD[r0i + j][g] = make_float4(sc_s, kv * fv0[j], kv * fv1[j], kv * fv2[j]);
    }

    // ---- p = sc @ W_pb ; P4 overwrites B4 ----
    float ps[4], pv0[4], pv1[4], pv2[4];
    {
        float bpb = b_pb_s[g];
        #pragma unroll
        for (int j = 0; j < 4; j++) { ps[j] = bpb; pv0[j] = pv1[j] = pv2[j] = 0.f; }
    }
    #pragma unroll 4
    for (int f = 0; f < 64; f++) {
        float wps = W_pb_s[f * 64 + g];
        float wpv = W_pb_v[f * 64 + g];
        #pragma unroll
        for (int j = 0; j < 4; j++) {
            float4 s = LD[r0i + j][f];
            ps[j]  += s.x * wps;
            pv0[j] += s.y * wpv;
            pv1[j] += s.z * wpv;
            pv2[j] += s.w * wpv;
        }
    }
    #pragma unroll
    for (int j = 0; j < 4; j++) {
        LE[r0i + j][g] = make_float4(ps[j], pv0[j], pv1[j], pv2[j]);
        out[OFF_PS + (nb + j) * 64 + g] = ps[j];
        out[OFF_PV + (size_t)(nb + j) * 192 + g * 3 + 0] = pv0[j];
        out[OFF_PV + (size_t)(nb + j) * 192 + g * 3 + 1] = pv1[j];
        out[OFF_PV + (size_t)(nb + j) * 192 + g * 3 + 2] = pv2[j];
    }

    // ---- r = p @ W_r1 ; readout ----
    float ra[4], rb[4], rv0[4], rv1[4], rv2[4];
    {
        float br0 = b_r1_s[g];
        float br1 = b_r1_s[g + 64];
        #pragma unroll
        for (int j = 0; j < 4; j++) { ra[j] = br0; rb[j] = br1; rv0[j] = rv1[j] = rv2[j] = 0.f; }
    }
    #pragma unroll 4
    for (int f = 0; f < 64; f++) {
        float w0  = W_r1_s[f * 128 + g];
        float w1  = W_r1_s[f * 128 + g + 64];
        float wrv = W_r1_v[f * 64 + g];
        #pragma unroll
        for (int j = 0; j < 4; j++) {
            float4 p = LE[r0i + j][f];
            ra[j]  += p.x * w0;
            rb[j]  += p.x * w1;
            rv0[j] += p.y * wrv;
            rv1[j] += p.z * wrv;
            rv2[j] += p.w * wrv;
        }
    }
    {
        float wr2s = W_r2_s[g];
        float wr2v = W_r2_v[g];
        float br2  = b_r2[0];
        #pragma unroll
        for (int j = 0; j < 4; j++) {
            float act  = silu(ra[j]);
            float gate = silu(rb[j]);
            float o_s = act * wr2s;
            float ov0 = gate * rv0[j] * wr2v;
            float ov1 = gate * rv1[j] * wr2v;
            float ov2 = gate * rv2[j] * wr2v;
            #pragma unroll
            for (int off = 32; off > 0; off >>= 1) {
                o_s += __shfl_down(o_s, off);
                ov0 += __shfl_down(ov0, off);
                ov1 += __shfl_down(ov1, off);
                ov2 += __shfl_down(ov2, off);
            }
            if (g == 0) {
                out[OFF_OS + (nb + j)] = o_s + br2;
                out[OFF_OV + (nb + j) * 3 + 0] = ov0;
                out[OFF_OV + (nb + j) * 3 + 1] = ov1;
                out[OFF_OV + (nb + j) * 3 + 2] = ov2;
            }
        }
    }
}

// ---------------------------------------------------------------------------
extern "C" void kernel_launch(void* const* d_in, const int* in_sizes, int n_in,
                              void* d_out, int out_size, void* d_ws, size_t ws_size,
                              hipStream_t stream)
{
    const float* vectors  = (const float*)d_in[0];
    const float* lengths  = (const float*)d_in[1];
    const float* node_s   = (const float*)d_in[2];
    const float* node_v   = (const float*)d_in[3];
    const float* sef      = (const float*)d_in[4];
    const int*  specie    = (const int*)d_in[5];
    const int*  senders   = (const int*)d_in[6];
    const int*  receivers = (const int*)d_in[7];
    const float* W_up_s   = (const float*)d_in[8];
    const float* b_up_s   = (const float*)d_in[9];
    const float* W_up_v   = (const float*)d_in[10];
    const float* mlp_W1   = (const float*)d_in[11];
    const float* mlp_b1   = (const float*)d_in[12];
    const float* mlp_W2   = (const float*)d_in[13];
    const float* mlp_b2   = (const float*)d_in[14];
    const float* mlp_W3   = (const float*)d_in[15];
    const float* mlp_b3   = (const float*)d_in[16];
    const float* W_dn_s   = (const float*)d_in[17];
    const float* b_dn_s   = (const float*)d_in[18];
    const float* W_dn_v   = (const float*)d_in[19];
    const float* w_sc_s   = (const float*)d_in[20];
    const float* w_sc_v   = (const float*)d_in[21];
    const float* W_pb_s   = (const float*)d_in[22];
    const float* b_pb_s   = (const float*)d_in[23];
    const float* W_pb_v   = (const float*)d_in[24];
    const float* W_r1_s   = (const float*)d_in[25];
    const float* b_r1_s   = (const float*)d_in[26];
    const float* W_r1_v   = (const float*)d_in[27];
    const float* W_r2_s   = (const float*)d_in[28];
    const float* b_r2     = (const float*)d_in[29];
    const float* W_r2_v   = (const float*)d_in[30];

    float* h_v   = (float*)d_ws;                                 // N*192 f32
    float* agg   = h_v + (size_t)N_ * 192;                       // N*448 f32
    ushort_t* hs_bf = (ushort_t*)(agg + (size_t)N_ * AGG_W);     // N*64 u16
    ushort_t* W1p   = hs_bf + (size_t)N_ * 64;
    ushort_t* W2p   = W1p + W1P_SZ;
    ushort_t* W3p   = W2p + W2P_SZ;
    int* eid        = (int*)((((size_t)(W3p + W3P_SZ)) + 15) & ~(size_t)15);  // E int
    int* cnt        = eid + E_;
    int* base       = cnt + N_;
    int* cursor     = base + N_;

    float* out = (float*)d_out;

    // pack first: it also zeroes agg + cnt (replaces 2 memset dispatches)
    pack_kernel<<<PACK_B + ZERO_B, 256, 0, stream>>>(
        mlp_W1, mlp_W2, mlp_W3, W1p, W2p, W3p, agg, cnt);

    up_kernel<<<N_ / 4, 64, 0, stream>>>(node_s, node_v, W_up_s, b_up_s, W_up_v,
                                         receivers, cnt, hs_bf, h_v);
    scan_kernel<<<1, 1024, 0, stream>>>(cnt, base, cursor);
    perm_kernel<<<E_ / 256, 256, 0, stream>>>(receivers, cursor, eid);

    edge_mlp_kernel<<<E_ / 64, 256, 0, stream>>>(
        lengths, sef, senders, receivers, vectors, eid,
        mlp_b1, mlp_b2, mlp_b3,
        hs_bf, h_v, W1p, W2p, W3p, agg);

    node_fused_kernel<<<N_ / 16, 256, 0, stream>>>(
        agg, specie,
        W_dn_s, b_dn_s, W_dn_v, w_sc_s, w_sc_v,
        W_pb_s, b_pb_s, W_pb_v, W_r1_s, b_r1_s, W_r1_v,
        W_r2_s, b_r2, W_r2_v, out);
}

// Round 15
// 339.868 us; speedup vs baseline: 1.0232x; 1.0232x over previous
//
#include <hip/hip_runtime.h>

typedef short bf16x8 __attribute__((ext_vector_type(8)));
typedef float f32x4  __attribute__((ext_vector_type(4)));
typedef unsigned short ushort_t;

__device__ __forceinline__ float silu(float x) {
    float t = __expf(-x);
    return x * __builtin_amdgcn_rcpf(1.f + t);
}

__device__ __forceinline__ ushort_t f2bs(float x) {
    union { float f; unsigned int u; } v; v.f = x;
    unsigned int r = v.u + 0x7FFF + ((v.u >> 16) & 1);
    return (ushort_t)(r >> 16);
}
__device__ __forceinline__ ushort_t f2bs_t(float x) {
    union { float f; unsigned int u; } v; v.f = x;
    return (ushort_t)(v.u >> 16);
}
__device__ __forceinline__ float bs2f(ushort_t x) {
    union { unsigned int u; float f; } v; v.u = ((unsigned int)x) << 16; return v.f;
}

// lgkm-only barrier: orders LDS ops across the workgroup WITHOUT draining
// vmcnt — global loads stay in flight across GEMM phases (T4 principle).
#define BAR_LGKM() do { \
    asm volatile("s_waitcnt lgkmcnt(0)" ::: "memory"); \
    __builtin_amdgcn_s_barrier(); \
} while (0)

constexpr int N_   = 16000;
constexpr int E_   = 256000;
constexpr int Fd   = 64;

constexpr float SQ3f    = 1.7320508075688772f;
constexpr float INV_SQ3 = 0.5773502691896258f;
constexpr float INV_SQ2 = 0.7071067811865476f;
constexpr float INV_AVG = 0.0625f;

constexpr int OFF_OS = 0;
constexpr int OFF_OV = N_;
constexpr int OFF_PS = OFF_OV + 3 * N_;
constexpr int OFF_PV = OFF_PS + N_ * Fd;

constexpr int W1P_SZ = 6 * 8 * 512;
constexpr int W2P_SZ = 4 * 8 * 512;
constexpr int W3P_SZ = 4 * 12 * 512;

// agg layout per node: [cs | kx | ky | kz | c0 | c1 | c2] x 64 features, f32
constexpr int AGG_W = 448;

// Single-union LDS: A/mix @0 stride 200 (12800 u = 25.6 KB); H1/H2 share @0
// stride 136 (GEMM2 carries outputs in registers across a barrier).
// launch_bounds (256,4): R7-R10 bisect showed the 2nd arg IS the effective
// residency; (256,4) is the verified clean operating point.
// Closed paths (journal): phase-4 h_v must stay SoA (R6/R11/R12 absmax
// failures); cross-GEMM prefetch spills (R3); occupancy>40% spills (R8);
// setprio neutral (R14). This is the verified session-best configuration.
constexpr int U_SZ = 12800;

// pack grid: 256 packing blocks + 448 zeroing blocks (agg + cnt)
constexpr int PACK_B  = 256;
constexpr int ZERO_B  = 448;
constexpr int AGG_F4  = (N_ * AGG_W) / 4;   // 1,792,000 float4
constexpr int CNT_I4  = N_ / 4;             // 4,000 int4

// ---------------------------------------------------------------------------
// pack weights fp32 -> bf16 MFMA B-fragment order; blocks >= PACK_B zero
// agg + cnt (replaces two hipMemsetAsync dispatches). Runs FIRST.
// ---------------------------------------------------------------------------
__global__ __launch_bounds__(256) void pack_kernel(
    const float* __restrict__ W1, const float* __restrict__ W2,
    const float* __restrict__ W3,
    ushort_t* __restrict__ W1p, ushort_t* __restrict__ W2p,
    ushort_t* __restrict__ W3p,
    float* __restrict__ agg, int* __restrict__ cnt)
{
    if (blockIdx.x >= PACK_B) {
        const int zb = blockIdx.x - PACK_B;
        const float4 zf = make_float4(0.f, 0.f, 0.f, 0.f);
        for (size_t i = (size_t)zb * 256 + threadIdx.x; i < (size_t)AGG_F4;
             i += (size_t)ZERO_B * 256)
            ((float4*)agg)[i] = zf;
        for (int i = zb * 256 + threadIdx.x; i < CNT_I4; i += ZERO_B * 256)
            ((int4*)cnt)[i] = make_int4(0, 0, 0, 0);
        return;
    }
    int idx = blockIdx.x * 256 + threadIdx.x;
    if (idx < W1P_SZ) {
        int j = idx & 7, lane = (idx >> 3) & 63, tile = idx >> 9;
        int c = tile >> 3, t = tile & 7;
        int k = c * 32 + (lane >> 4) * 8 + j;
        int n = t * 16 + (lane & 15);
        W1p[idx] = f2bs(k < 161 ? W1[k * 128 + n] : 0.f);
    } else if (idx < W1P_SZ + W2P_SZ) {
        int q = idx - W1P_SZ;
        int j = q & 7, lane = (q >> 3) & 63, tile = q >> 9;
        int c = tile >> 3, t = tile & 7;
        int k = c * 32 + (lane >> 4) * 8 + j;
        int n = t * 16 + (lane & 15);
        W2p[q] = f2bs(W2[k * 128 + n]);
    } else {
        int q = idx - W1P_SZ - W2P_SZ;
        int j = q & 7, lane = (q >> 3) & 63, tile = q >> 9;
        int c = tile / 12, t = tile % 12;
        int k = c * 32 + (lane >> 4) * 8 + j;
        int n = t * 16 + (lane & 15);
        W3p[q] = f2bs(W3[k * 192 + n]);
    }
}

// ---------------------------------------------------------------------------
// Kernel 1: up-projection, 4 nodes/block. h_s bf16; h_v fp32 SoA (verified
// layout: h_v[n*192 + c*64 + g]). Fused receiver-count.
// ---------------------------------------------------------------------------
__global__ __launch_bounds__(64, 4) void up_kernel(
    const float* __restrict__ node_s, const float* __restrict__ node_v,
    const float* __restrict__ W_up_s, const float* __restrict__ b_up_s,
    const float* __restrict__ W_up_v,
    const int* __restrict__ receivers, int* __restrict__ cnt,
    ushort_t* __restrict__ hs_bf, float* __restrict__ h_v)
{
    __shared__ float ns[4][64];
    __shared__ float nv[4][64][3];
    const int n0 = blockIdx.x * 4;
    const int g  = threadIdx.x;

    {
        int e = blockIdx.x * 64 + g;
        atomicAdd(&cnt[receivers[e]], 1);
    }

    #pragma unroll
    for (int j = 0; j < 4; j++) ns[j][g] = node_s[(n0 + j) * 64 + g];
    for (int idx = g; idx < 4 * 192; idx += 64) {
        int j = idx / 192, r = idx - j * 192;
        nv[j][r / 3][r % 3] = node_v[(size_t)n0 * 192 + idx];
    }
    __syncthreads();

    float as[4], a0[4], a1[4], a2[4];
    float bb = b_up_s[g];
    #pragma unroll
    for (int j = 0; j < 4; j++) { as[j] = bb; a0[j] = a1[j] = a2[j] = 0.f; }
    #pragma unroll 4
    for (int f = 0; f < 64; f++) {
        float wss = W_up_s[f * 64 + g];
        float wv  = W_up_v[f * 64 + g];
        #pragma unroll
        for (int j = 0; j < 4; j++) {
            as[j] += ns[j][f] * wss;
            a0[j] += nv[j][f][0] * wv;
            a1[j] += nv[j][f][1] * wv;
            a2[j] += nv[j][f][2] * wv;
        }
    }
    #pragma unroll
    for (int j = 0; j < 4; j++) {
        hs_bf[(n0 + j) * 64 + g] = f2bs(as[j]);
        h_v[(n0 + j) * 192 + 0 * 64 + g] = a0[j];
        h_v[(n0 + j) * 192 + 1 * 64 + g] = a1[j];
        h_v[(n0 + j) * 192 + 2 * 64 + g] = a2[j];
    }
}

// ---------------------------------------------------------------------------
// CSR scan
// ---------------------------------------------------------------------------
__global__ __launch_bounds__(1024) void scan_kernel(
    const int* __restrict__ cnt, int* __restrict__ base, int* __restrict__ cursor)
{
    __shared__ int part[1024];
    const int t = threadIdx.x;
    int v[16];
    int s = 0;
    if (t < 1000) {
        const int4* c4 = (const int4*)(cnt + t * 16);
        #pragma unroll
        for (int q = 0; q < 4; q++) {
            int4 w = c4[q];
            v[q * 4 + 0] = w.x; v[q * 4 + 1] = w.y;
            v[q * 4 + 2] = w.z; v[q * 4 + 3] = w.w;
            s += w.x + w.y + w.z + w.w;
        }
    }
    part[t] = s;
    __syncthreads();
    for (int off = 1; off < 1024; off <<= 1) {
        int u = (t >= off) ? part[t - off] : 0;
        __syncthreads();
        part[t] += u;
        __syncthreads();
    }
    if (t < 1000) {
        int run = part[t] - s;
        int b[16];
        #pragma unroll
        for (int i = 0; i < 16; i++) { b[i] = run; run += v[i]; }
        int4* bb = (int4*)(base + t * 16);
        int4* cc = (int4*)(cursor + t * 16);
        #pragma unroll
        for (int q = 0; q < 4; q++) {
            int4 w = { b[q * 4], b[q * 4 + 1], b[q * 4 + 2], b[q * 4 + 3] };
            bb[q] = w;
            cc[q] = w;
        }
    }
}

// ---------------------------------------------------------------------------
// inverse permutation: eid[p] = original edge id of sorted position p
// ---------------------------------------------------------------------------
__global__ __launch_bounds__(256) void perm_kernel(
    const int* __restrict__ receivers, int* __restrict__ cursor,
    int* __restrict__ eid)
{
    int e = blockIdx.x * 256 + threadIdx.x;
    int r = receivers[e];
    int p = atomicAdd(&cursor[r], 1);
    eid[p] = e;
}

// ---------------------------------------------------------------------------
// Kernel 2: cooperative MFMA edge MLP over CSR-SORTED edges + in-register
// segmented reduction. Single 25.6 KB union LDS; (256,4) launch_bounds
// (verified-best codegen, ~101 us). 7 lgkm-only barriers.
// ---------------------------------------------------------------------------
__global__ __launch_bounds__(256, 4) void edge_mlp_kernel(
    const float* __restrict__ lengths, const float* __restrict__ sef,
    const int* __restrict__ senders, const int* __restrict__ receivers,
    const float* __restrict__ vectors, const int* __restrict__ eid,
    const float* __restrict__ b1f, const float* __restrict__ b2f,
    const float* __restrict__ b3f,
    const ushort_t* __restrict__ hs_bf, const float* __restrict__ h_v,
    const ushort_t* __restrict__ W1p, const ushort_t* __restrict__ W2p,
    const ushort_t* __restrict__ W3p,
    float* __restrict__ agg)
{
    __shared__ ushort_t U[U_SZ];    // A/mix (stride 200) | H1/H2 @0 (stride 136)
    __shared__ int snd_s[64];
    __shared__ int rcv_s[64];
    __shared__ float ev_s[64][3];

    const int tid  = threadIdx.x;
    const int wave = tid >> 6, lane = tid & 63;
    const int quad = lane >> 4, l4 = lane & 15;
    const int e0   = blockIdx.x * 64;   // sorted-position base

    if (tid < 64) {
        int e = eid[e0 + tid];
        snd_s[tid] = senders[e];
        rcv_s[tid] = receivers[e];
        ev_s[tid][0] = SQ3f * vectors[e * 3 + 0];
        ev_s[tid][1] = SQ3f * vectors[e * 3 + 1];
        ev_s[tid][2] = SQ3f * vectors[e * 3 + 2];
    }

    // ---- stage mlp_in rows (sorted order): 64 edges x 192 bf16 (pad 200) ----
    {
        const int e  = tid & 63;
        const int ge = eid[e0 + e];
        const int snd = senders[ge];
        const int rcv = receivers[ge];
        for (int c = tid >> 6; c < 24; c += 4) {
            bf16x8 v;
            if (c < 8) {
                v = *(const bf16x8*)(hs_bf + snd * 64 + c * 8);
            } else if (c < 16) {
                v = *(const bf16x8*)(hs_bf + rcv * 64 + (c - 8) * 8);
            } else if (c < 20) {
                const float4 s0 = *(const float4*)(sef + (size_t)ge * 32 + (c - 16) * 8);
                const float4 s1 = *(const float4*)(sef + (size_t)ge * 32 + (c - 16) * 8 + 4);
                v[0] = (short)f2bs(s0.x); v[1] = (short)f2bs(s0.y);
                v[2] = (short)f2bs(s0.z); v[3] = (short)f2bs(s0.w);
                v[4] = (short)f2bs(s1.x); v[5] = (short)f2bs(s1.y);
                v[6] = (short)f2bs(s1.z); v[7] = (short)f2bs(s1.w);
            } else if (c == 20) {
                v = (bf16x8){0,0,0,0,0,0,0,0};
                v[0] = (short)f2bs(lengths[ge]);
            } else {
                v = (bf16x8){0,0,0,0,0,0,0,0};
            }
            *(bf16x8*)(&U[e * 200 + c * 8]) = v;
        }
    }
    BAR_LGKM();   // (1) A + snd/rcv/ev ready

    const bf16x8* B1 = (const bf16x8*)W1p;
    const bf16x8* B2 = (const bf16x8*)W2p;
    const bf16x8* B3 = (const bf16x8*)W3p;

    // ---- GEMM1: wave owns N-tiles {2w, 2w+1}; M = 64 edges ----
    {
        f32x4 acc[2][4];
        #pragma unroll
        for (int ti = 0; ti < 2; ti++)
            #pragma unroll
            for (int m = 0; m < 4; m++) acc[ti][m] = (f32x4){0,0,0,0};
        #pragma unroll
        for (int c = 0; c < 6; c++) {
            bf16x8 b0 = B1[(c * 8 + wave * 2 + 0) * 64 + lane];
            bf16x8 b1 = B1[(c * 8 + wave * 2 + 1) * 64 + lane];
            #pragma unroll
            for (int m = 0; m < 4; m++) {
                bf16x8 a = *(const bf16x8*)(&U[(m * 16 + l4) * 200 + c * 32 + quad * 8]);
                acc[0][m] = __builtin_amdgcn_mfma_f32_16x16x32_bf16(a, b0, acc[0][m], 0, 0, 0);
                acc[1][m] = __builtin_amdgcn_mfma_f32_16x16x32_bf16(a, b1, acc[1][m], 0, 0, 0);
            }
        }
        BAR_LGKM();   // (2) all waves done reading A
        #pragma unroll
        for (int ti = 0; ti < 2; ti++) {
            int t = wave * 2 + ti;
            float bb = b1f[t * 16 + l4];
            #pragma unroll
            for (int m = 0; m < 4; m++)
                #pragma unroll
                for (int r = 0; r < 4; r++)
                    U[(m * 16 + quad * 4 + r) * 136 + t * 16 + l4] =
                        f2bs_t(silu(acc[ti][m][r] + bb));
        }
    }
    BAR_LGKM();   // (3) H1 ready

    // ---- GEMM2: read H1 @0; hold H2 in registers across barrier; write
    //      H2 @0 over H1 (single shared H region) ----
    {
        f32x4 acc[2][4];
        #pragma unroll
        for (int ti = 0; ti < 2; ti++)
            #pragma unroll
            for (int m = 0; m < 4; m++) acc[ti][m] = (f32x4){0,0,0,0};
        #pragma unroll
        for (int c = 0; c < 4; c++) {
            bf16x8 b0 = B2[(c * 8 + wave * 2 + 0) * 64 + lane];
            bf16x8 b1 = B2[(c * 8 + wave * 2 + 1) * 64 + lane];
            #pragma unroll
            for (int m = 0; m < 4; m++) {
                bf16x8 a = *(const bf16x8*)(&U[(m * 16 + l4) * 136 + c * 32 + quad * 8]);
                acc[0][m] = __builtin_amdgcn_mfma_f32_16x16x32_bf16(a, b0, acc[0][m], 0, 0, 0);
                acc[1][m] = __builtin_amdgcn_mfma_f32_16x16x32_bf16(a, b1, acc[1][m], 0, 0, 0);
            }
        }
        BAR_LGKM();   // (4) all waves done reading H1
        #pragma unroll
        for (int ti = 0; ti < 2; ti++) {
            int t = wave * 2 + ti;
            float bb = b2f[t * 16 + l4];
            #pragma unroll
            for (int m = 0; m < 4; m++)
                #pragma unroll
                for (int r = 0; r < 4; r++)
                    U[(m * 16 + quad * 4 + r) * 136 + t * 16 + l4] =
                        f2bs_t(silu(acc[ti][m][r] + bb));
        }
    }
    BAR_LGKM();   // (5) H2 ready

    // ---- GEMM3: read H2 @0; mix -> stride 200 @0 after barrier ----
    {
        f32x4 acc[3][4];
        #pragma unroll
        for (int ti = 0; ti < 3; ti++)
            #pragma unroll
            for (int m = 0; m < 4; m++) acc[ti][m] = (f32x4){0,0,0,0};
        #pragma unroll
        for (int c = 0; c < 4; c++) {
            bf16x8 b0 = B3[(c * 12 + wave * 3 + 0) * 64 + lane];
            bf16x8 b1 = B3[(c * 12 + wave * 3 + 1) * 64 + lane];
            bf16x8 b2 = B3[(c * 12 + wave * 3 + 2) * 64 + lane];
            #pragma unroll
            for (int m = 0; m < 4; m++) {
                bf16x8 a = *(const bf16x8*)(&U[(m * 16 + l4) * 136 + c * 32 + quad * 8]);
                acc[0][m] = __builtin_amdgcn_mfma_f32_16x16x32_bf16(a, b0, acc[0][m], 0, 0, 0);
                acc[1][m] = __builtin_amdgcn_mfma_f32_16x16x32_bf16(a, b1, acc[1][m], 0, 0, 0);
                acc[2][m] = __builtin_amdgcn_mfma_f32_16x16x32_bf16(a, b2, acc[2][m], 0, 0, 0);
            }
        }
        BAR_LGKM();   // (6) all waves done reading H2
        #pragma unroll
        for (int ti = 0; ti < 3; ti++) {
            int t = wave * 3 + ti;
            float bb = b3f[t * 16 + l4];
            #pragma unroll
            for (int m = 0; m < 4; m++)
                #pragma unroll
                for (int r = 0; r < 4; r++)
                    U[(m * 16 + quad * 4 + r) * 200 + t * 16 + l4] =
                        f2bs(acc[ti][m][r] + bb);
        }
    }
    BAR_LGKM();   // (7) mix ready

    // ---- Phase 4: segmented reduction over receiver runs (verified form,
    //      SoA scalar gathers, 8-deep batches). ----
    {
        const int g  = lane;
        const int p0 = wave * 16;
        float acc0 = 0.f, acc1 = 0.f, acc2 = 0.f, acc3 = 0.f;
        float acc4 = 0.f, acc5 = 0.f, acc6 = 0.f;
        int cur = rcv_s[p0];

        for (int jj = 0; jj < 16; jj += 8) {
            float M0[8], M1[8], M2[8], MS[8];
            #pragma unroll
            for (int j = 0; j < 8; j++) {
                const int se = snd_s[p0 + jj + j];
                M0[j] = h_v[(size_t)se * 192 + 0 * 64 + g];
                M1[j] = h_v[(size_t)se * 192 + 1 * 64 + g];
                M2[j] = h_v[(size_t)se * 192 + 2 * 64 + g];
                MS[j] = bs2f(hs_bf[se * 64 + g]);
            }
            #pragma unroll
            for (int j = 0; j < 8; j++) {
                const int el = p0 + jj + j;
                const int r  = rcv_s[el];
                if (r != cur) {
                    float* a = agg + (size_t)cur * AGG_W + g;
                    atomicAdd(a +   0, acc0); atomicAdd(a +  64, acc1);
                    atomicAdd(a + 128, acc2); atomicAdd(a + 192, acc3);
                    atomicAdd(a + 256, acc4); atomicAdd(a + 320, acc5);
                    atomicAdd(a + 384, acc6);
                    acc0 = acc1 = acc2 = acc3 = acc4 = acc5 = acc6 = 0.f;
                    cur = r;
                }
                const float ev0 = ev_s[el][0], ev1 = ev_s[el][1], ev2 = ev_s[el][2];
                const float mixs  = bs2f(U[el * 200 +   0 + g]);
                const float mixv1 = bs2f(U[el * 200 +  64 + g]);
                const float mixv2 = bs2f(U[el * 200 + 128 + g]);
                const float k = MS[j] * mixv1;
                acc0 += (M0[j] * ev0 + M1[j] * ev1 + M2[j] * ev2) * mixs;
                acc1 += k * ev0;
                acc2 += k * ev1;
                acc3 += k * ev2;
                acc4 += (M1[j] * ev2 - M2[j] * ev1) * mixv2;
                acc5 += (M2[j] * ev0 - M0[j] * ev2) * mixv2;
                acc6 += (M0[j] * ev1 - M1[j] * ev0) * mixv2;
            }
        }
        float* a = agg + (size_t)cur * AGG_W + g;
        atomicAdd(a +   0, acc0); atomicAdd(a +  64, acc1);
        atomicAdd(a + 128, acc2); atomicAdd(a + 192, acc3);
        atomicAdd(a + 256, acc4); atomicAdd(a + 320, acc5);
        atomicAdd(a + 384, acc6);
    }
}

// ---------------------------------------------------------------------------
// Kernel 3: node tail (verified form: 16 nodes/block, 4/wave, float4 LDS,
// zero barriers).
// ---------------------------------------------------------------------------
__global__ __launch_bounds__(256, 4) void node_fused_kernel(
    const float* __restrict__ agg,
    const int* __restrict__ specie,
    const float* __restrict__ W_dn_s, const float* __restrict__ b_dn_s,
    const float* __restrict__ W_dn_v,
    const float* __restrict__ w_sc_s, const float* __restrict__ w_sc_v,
    const float* __restrict__ W_pb_s, const float* __restrict__ b_pb_s,
    const float* __restrict__ W_pb_v,
    const float* __restrict__ W_r1_s, const float* __restrict__ b_r1_s,
    const float* __restrict__ W_r1_v,
    const float* __restrict__ W_r2_s, const float* __restrict__ b_r2,
    const float* __restrict__ W_r2_v,
    float* __restrict__ out)
{
    __shared__ float4 LD[16][64];   // A4 {as, av0..2 rows 0..63}, then SC4
    __shared__ float4 LE[16][64];   // B4 {0, av0..2 rows 64..127}, then P4

    const int tid = threadIdx.x;
    const int w   = tid >> 6;
    const int g   = tid & 63;
    const int nb  = blockIdx.x * 16 + w * 4;   // first node of this wave
    const int r0i = w * 4;                      // wave's LDS row base

    // ---- stage packed aggregates (coalesced 7 loads/node/lane) ----
    #pragma unroll
    for (int j = 0; j < 4; j++) {
        const float* ag = agg + (size_t)(nb + j) * AGG_W;
        float a0 = ag[g], a1 = ag[64 + g], a2 = ag[128 + g], a3 = ag[192 + g];
        float b1 = ag[256 + g], b2 = ag[320 + g], b3 = ag[384 + g];
        LD[r0i + j][g] = make_float4(a0 * (INV_SQ3 * INV_AVG),
                                     a1 * INV_AVG, a2 * INV_AVG, a3 * INV_AVG);
        LE[r0i + j][g] = make_float4(0.f,
                                     b1 * (INV_SQ2 * INV_AVG),
                                     b2 * (INV_SQ2 * INV_AVG),
                                     b3 * (INV_SQ2 * INV_AVG));
    }
    // wave-private LDS: no barrier needed anywhere in this kernel

    // ---- f_s = as @ W_dn_s ; f_v = av @ W_dn_v (128 rows folded 2x64) ----
    float fs[4], fv0[4], fv1[4], fv2[4];
    {
        float bds = b_dn_s[g];
        #pragma unroll
        for (int j = 0; j < 4; j++) { fs[j] = bds; fv0[j] = fv1[j] = fv2[j] = 0.f; }
    }
    #pragma unroll 4
    for (int f = 0; f < 64; f++) {
        float ws  = W_dn_s[f * 64 + g];
        float wva = W_dn_v[f * 64 + g];
        float wvb = W_dn_v[(64 + f) * 64 + g];
        #pragma unroll
        for (int j = 0; j < 4; j++) {
            float4 a = LD[r0i + j][f];
            float4 b = LE[r0i + j][f];
            fs[j]  += a.x * ws;
            fv0[j] += a.y * wva + b.y * wvb;
            fv1[j] += a.z * wva + b.z * wvb;
            fv2[j] += a.w * wva + b.w * wvb;
        }
    }

    // ---- elementwise specie mix; SC4 overwrites A4 (wave-private) ----
    #pragma unroll
    for (int j = 0; j < 4; j++) {
        int sp = specie[nb + j];
        float vv = (fv0[j] * fv0[j] + fv1[j] * fv1[j] + fv2[j] * fv2[j]) * INV_SQ3;
        float ws0 = w_sc_s[sp * 192 +   0 + g];
        float ws1 = w_sc_s[sp * 192 +  64 + g];
        float ws2 = w_sc_s[sp * 192 + 128 + g];
        float wv0 = w_sc_v[sp * 128 +   0 + g];
        float wv1 = w_sc_v[sp * 128 +  64 + g];
        float sc_s = ws0 * fs[j] + ws1 * fs[j] * fs[j] + ws2 * vv;
        float kv = wv0 + wv1 * fs[j];
        LD[r0i + j][g] = make_float4(sc_s, kv * fv0[j], kv * fv1[j], kv * fv2[j]);
    }

    // ---- p = sc @ W_pb ; P4 overwrites B4 ----
    float ps[4], pv0[4], pv1[4], pv2[4];
    {
        float bpb = b_pb_s[g];
        #pragma unroll
        for (int j = 0; j < 4; j++) { ps[j] = bpb; pv0[j] = pv1[j] = pv2[j] = 0.f; }
    }
    #pragma unroll 4
    for (int f = 0; f < 64; f++) {
        float wps = W_pb_s[f * 64 + g];
        float wpv = W_pb_v[f * 64 + g];
        #pragma unroll
        for (int j = 0; j < 4; j++) {
            float4 s = LD[r0i + j][f];
            ps[j]  += s.x * wps;
            pv0[j] += s.y * wpv;
            pv1[j] += s.z * wpv;
            pv2[j] += s.w * wpv;
        }
    }
    #pragma unroll
    for (int j = 0; j < 4; j++) {
        LE[r0i + j][g] = make_float4(ps[j], pv0[j], pv1[j], pv2[j]);
        out[OFF_PS + (nb + j) * 64 + g] = ps[j];
        out[OFF_PV + (size_t)(nb + j) * 192 + g * 3 + 0] = pv0[j];
        out[OFF_PV + (size_t)(nb + j) * 192 + g * 3 + 1] = pv1[j];
        out[OFF_PV + (size_t)(nb + j) * 192 + g * 3 + 2] = pv2[j];
    }

    // ---- r = p @ W_r1 ; readout ----
    float ra[4], rb[4], rv0[4], rv1[4], rv2[4];
    {
        float br0 = b_r1_s[g];
        float br1 = b_r1_s[g + 64];
        #pragma unroll
        for (int j = 0; j < 4; j++) { ra[j] = br0; rb[j] = br1; rv0[j] = rv1[j] = rv2[j] = 0.f; }
    }
    #pragma unroll 4
    for (int f = 0; f < 64; f++) {
        float w0  = W_r1_s[f * 128 + g];
        float w1  = W_r1_s[f * 128 + g + 64];
        float wrv = W_r1_v[f * 64 + g];
        #pragma unroll
        for (int j = 0; j < 4; j++) {
            float4 p = LE[r0i + j][f];
            ra[j]  += p.x * w0;
            rb[j]  += p.x * w1;
            rv0[j] += p.y * wrv;
            rv1[j] += p.z * wrv;
            rv2[j] += p.w * wrv;
        }
    }
    {
        float wr2s = W_r2_s[g];
        float wr2v = W_r2_v[g];
        float br2  = b_r2[0];
        #pragma unroll
        for (int j = 0; j < 4; j++) {
            float act  = silu(ra[j]);
            float gate = silu(rb[j]);
            float o_s = act * wr2s;
            float ov0 = gate * rv0[j] * wr2v;
            float ov1 = gate * rv1[j] * wr2v;
            float ov2 = gate * rv2[j] * wr2v;
            #pragma unroll
            for (int off = 32; off > 0; off >>= 1) {
                o_s += __shfl_down(o_s, off);
                ov0 += __shfl_down(ov0, off);
                ov1 += __shfl_down(ov1, off);
                ov2 += __shfl_down(ov2, off);
            }
            if (g == 0) {
                out[OFF_OS + (nb + j)] = o_s + br2;
                out[OFF_OV + (nb + j) * 3 + 0] = ov0;
                out[OFF_OV + (nb + j) * 3 + 1] = ov1;
                out[OFF_OV + (nb + j) * 3 + 2] = ov2;
            }
        }
    }
}

// ---------------------------------------------------------------------------
extern "C" void kernel_launch(void* const* d_in, const int* in_sizes, int n_in,
                              void* d_out, int out_size, void* d_ws, size_t ws_size,
                              hipStream_t stream)
{
    const float* vectors  = (const float*)d_in[0];
    const float* lengths  = (const float*)d_in[1];
    const float* node_s   = (const float*)d_in[2];
    const float* node_v   = (const float*)d_in[3];
    const float* sef      = (const float*)d_in[4];
    const int*  specie    = (const int*)d_in[5];
    const int*  senders   = (const int*)d_in[6];
    const int*  receivers = (const int*)d_in[7];
    const float* W_up_s   = (const float*)d_in[8];
    const float* b_up_s   = (const float*)d_in[9];
    const float* W_up_v   = (const float*)d_in[10];
    const float* mlp_W1   = (const float*)d_in[11];
    const float* mlp_b1   = (const float*)d_in[12];
    const float* mlp_W2   = (const float*)d_in[13];
    const float* mlp_b2   = (const float*)d_in[14];
    const float* mlp_W3   = (const float*)d_in[15];
    const float* mlp_b3   = (const float*)d_in[16];
    const float* W_dn_s   = (const float*)d_in[17];
    const float* b_dn_s   = (const float*)d_in[18];
    const float* W_dn_v   = (const float*)d_in[19];
    const float* w_sc_s   = (const float*)d_in[20];
    const float* w_sc_v   = (const float*)d_in[21];
    const float* W_pb_s   = (const float*)d_in[22];
    const float* b_pb_s   = (const float*)d_in[23];
    const float* W_pb_v   = (const float*)d_in[24];
    const float* W_r1_s   = (const float*)d_in[25];
    const float* b_r1_s   = (const float*)d_in[26];
    const float* W_r1_v   = (const float*)d_in[27];
    const float* W_r2_s   = (const float*)d_in[28];
    const float* b_r2     = (const float*)d_in[29];
    const float* W_r2_v   = (const float*)d_in[30];

    float* h_v   = (float*)d_ws;                                 // N*192 f32
    float* agg   = h_v + (size_t)N_ * 192;                       // N*448 f32
    ushort_t* hs_bf = (ushort_t*)(agg + (size_t)N_ * AGG_W);     // N*64 u16
    ushort_t* W1p   = hs_bf + (size_t)N_ * 64;
    ushort_t* W2p   = W1p + W1P_SZ;
    ushort_t* W3p   = W2p + W2P_SZ;
    int* eid        = (int*)((((size_t)(W3p + W3P_SZ)) + 15) & ~(size_t)15);  // E int
    int* cnt        = eid + E_;
    int* base       = cnt + N_;
    int* cursor     = base + N_;

    float* out = (float*)d_out;

    // pack first: it also zeroes agg + cnt (replaces 2 memset dispatches)
    pack_kernel<<<PACK_B + ZERO_B, 256, 0, stream>>>(
        mlp_W1, mlp_W2, mlp_W3, W1p, W2p, W3p, agg, cnt);

    up_kernel<<<N_ / 4, 64, 0, stream>>>(node_s, node_v, W_up_s, b_up_s, W_up_v,
                                         receivers, cnt, hs_bf, h_v);
    scan_kernel<<<1, 1024, 0, stream>>>(cnt, base, cursor);
    perm_kernel<<<E_ / 256, 256, 0, stream>>>(receivers, cursor, eid);

    edge_mlp_kernel<<<E_ / 64, 256, 0, stream>>>(
        lengths, sef, senders, receivers, vectors, eid,
        mlp_b1, mlp_b2, mlp_b3,
        hs_bf, h_v, W1p, W2p, W3p, agg);

    node_fused_kernel<<<N_ / 16, 256, 0, stream>>>(
        agg, specie,
        W_dn_s, b_dn_s, W_dn_v, w_sc_s, w_sc_v,
        W_pb_s, b_pb_s, W_pb_v, W_r1_s, b_r1_s, W_r1_v,
        W_r2_s, b_r2, W_r2_v, out);
}